// Round 12
// baseline (156.607 us; speedup 1.0000x reference)
//
#include <hip/hip_runtime.h>

#define HID 32
#define SH 9                 // bucket covers 512 nodes
#define BNODES 512
#define NBMAX 320            // >= ceil(150000/512)=293
#define TILE 8192            // edges per bucketize block

typedef unsigned int uint;

__device__ __forceinline__ uint f2bf(float v) {   // RNE f32 -> bf16 bits
    uint b = __float_as_uint(v);
    return (b + 0x7fffu + ((b >> 16) & 1u)) >> 16;
}

// ---- zero bcnt+bcur (replaces hipMemsetAsync) ----
__global__ void k_zero(int* __restrict__ p, int n) {
    int i = blockIdx.x * 256 + threadIdx.x;
    if (i < n) p[i] = 0;
}

// ---- per-tile bucket counting: LDS hist then one global atomic per bucket ----
__global__ void __launch_bounds__(512) k_bcount(const int* __restrict__ dst,
                                                int* __restrict__ bcnt, int E, int NB) {
    __shared__ int c[NBMAX];
    for (int b = threadIdx.x; b < NBMAX; b += 512) c[b] = 0;
    __syncthreads();
    int base = blockIdx.x * TILE;
    for (int k = 0; k < TILE / 512; ++k) {
        int i = base + k * 512 + threadIdx.x;
        if (i < E) atomicAdd(&c[dst[i] >> SH], 1);
    }
    __syncthreads();
    for (int b = threadIdx.x; b < NB; b += 512)
        if (c[b]) atomicAdd(&bcnt[b], c[b]);
}

// ---- exclusive scan of bucket counts; also writes rowptr[N] = E ----
__global__ void k_scanb(const int* __restrict__ bcnt, int* __restrict__ bbase,
                        int* __restrict__ rowptr, int N, int NB) {
    __shared__ int l[NBMAX + 1];
    int tid = threadIdx.x;
    if (tid < 64) {
        int lo = tid * 5;
        int s = 0;
        for (int b = lo; b < lo + 5 && b < NB; ++b) s += bcnt[b];
        int v = s;
        for (int off = 1; off < 64; off <<= 1) {
            int u = __shfl_up(v, off, 64);
            if (tid >= off) v += u;
        }
        int excl = v - s;
        for (int b = lo; b < lo + 5 && b < NB; ++b) { l[b] = excl; excl += bcnt[b]; }
        if (tid == 63) l[NB] = excl;
    }
    __syncthreads();
    for (int b = tid; b <= NB; b += blockDim.x) bbase[b] = l[b];
    if (tid == 0) rowptr[N] = l[NB];
}

// ---- bucketize: tile -> LDS counting sort by bucket -> contiguous chunk append to ebuf ----
// packed edge word: src | (dlow << 18)   (src < 2^18, dlow < 512)
__global__ void __launch_bounds__(512) k_bucketize(
        const int* __restrict__ src, const int* __restrict__ dst,
        const int* __restrict__ bbase, int* __restrict__ bcur,
        uint* __restrict__ ebuf, int E, int NB) {
    __shared__ uint  ecache[TILE];
    __shared__ unsigned short bcache[TILE];
    __shared__ int cnt[NBMAX];       // tile-local counts, then cursor
    __shared__ int loff[NBMAX + 1];  // tile-local exclusive offsets
    __shared__ int gbase[NBMAX];     // reserved global base per bucket
    int tid = threadIdx.x;
    int tbase = blockIdx.x * TILE;
    int tcount = min(E - tbase, TILE);

    for (int b = tid; b < NBMAX; b += 512) cnt[b] = 0;
    __syncthreads();
    // phase 1: count
    for (int k = 0; k < TILE / 512; ++k) {
        int i = tbase + k * 512 + tid;
        if (i < E) atomicAdd(&cnt[dst[i] >> SH], 1);
    }
    __syncthreads();
    // phase 2: scan (wave 0)
    if (tid < 64) {
        int lo = tid * 5;
        int s = 0;
        for (int b = lo; b < lo + 5 && b < NB; ++b) s += cnt[b];
        int v = s;
        for (int off = 1; off < 64; off <<= 1) {
            int u = __shfl_up(v, off, 64);
            if (tid >= off) v += u;
        }
        int excl = v - s;
        for (int b = lo; b < lo + 5 && b < NB; ++b) { loff[b] = excl; excl += cnt[b]; }
        if (tid == 63) loff[NB] = excl;
    }
    __syncthreads();
    // cursor = loff copy
    for (int b = tid; b < NB; b += 512) cnt[b] = loff[b];
    __syncthreads();
    // phase 3: place into LDS ordered by bucket
    for (int k = 0; k < TILE / 512; ++k) {
        int i = tbase + k * 512 + tid;
        if (i < E) {
            int d = dst[i];
            int b = d >> SH;
            int pos = atomicAdd(&cnt[b], 1);
            ecache[pos] = (uint)src[i] | ((uint)(d & (BNODES - 1)) << 18);
            bcache[pos] = (unsigned short)b;
        }
    }
    __syncthreads();
    // phase 4: reserve global chunks
    for (int b = tid; b < NB; b += 512) {
        int tc = loff[b + 1] - loff[b];
        if (tc > 0) gbase[b] = bbase[b] + atomicAdd(&bcur[b], tc);
    }
    __syncthreads();
    // phase 5: contiguous write-out
    for (int j = tid; j < tcount; j += 512) {
        int b = bcache[j];
        ebuf[gbase[b] + (j - loff[b])] = ecache[j];
    }
}

// ---- per-bucket counting sort by node: emits rowptr, dinv, p1 = x*dinv, dst-sorted col ----
__global__ void __launch_bounds__(512) k_sortb(
        const uint* __restrict__ ebuf, const int* __restrict__ bbase,
        const float* __restrict__ x,
        int* __restrict__ rowptr, float* __restrict__ dinv,
        float2* __restrict__ p1, int* __restrict__ col, int N) {
    __shared__ int c[BNODES];    // per-node counts
    __shared__ int off[BNODES];  // exclusive offsets within bucket
    __shared__ int cur[BNODES];  // placement cursors
    int b = blockIdx.x, tid = threadIdx.x;
    int base = bbase[b], cnt = bbase[b + 1] - base;
    for (int t = tid; t < BNODES; t += 512) c[t] = 0;
    __syncthreads();
    for (int j = tid; j < cnt; j += 512)
        atomicAdd(&c[ebuf[base + j] >> 18], 1);
    __syncthreads();
    // scan 512 counters: 64 lanes x 8 each (wave 0)
    if (tid < 64) {
        int lo = tid * 8, s = 0;
#pragma unroll
        for (int k = 0; k < 8; ++k) s += c[lo + k];
        int v = s;
        for (int o = 1; o < 64; o <<= 1) {
            int u = __shfl_up(v, o, 64);
            if (tid >= o) v += u;
        }
        int excl = v - s;
#pragma unroll
        for (int k = 0; k < 8; ++k) { off[lo + k] = excl; excl += c[lo + k]; }
    }
    __syncthreads();
    for (int t = tid; t < BNODES; t += 512) {
        cur[t] = off[t];
        int node = (b << SH) + t;
        if (node < N) {
            rowptr[node] = base + off[t];
            float di = rsqrtf((float)c[t] + 1.0f);
            dinv[node] = di;
            float2 xv = ((const float2*)x)[node];
            p1[node] = make_float2(xv.x * di, xv.y * di);
        }
    }
    __syncthreads();
    for (int j = tid; j < cnt; j += 512) {
        uint e = ebuf[base + j];
        int dl = e >> 18;
        int pos = atomicAdd(&cur[dl], 1);
        col[base + pos] = (int)(e & 0x3FFFF);
    }
}

// ---- FUSED layer-1 gather + W1/ReLU/W2/pre-scale -> packed bf16 p2 rows ----
// 4 lanes per node: lanes stride the edge list (coalesced col reads, 4x MLP
// latency hiding); shfl-reduce within the 4-lane group; lane 0 runs the MLP.
__global__ void __launch_bounds__(256) k_gl12(
        const int* __restrict__ rowptr, const int* __restrict__ col,
        const float2* __restrict__ p1, const float* __restrict__ dinv,
        const float* __restrict__ W1, const float* __restrict__ b1,
        const float* __restrict__ W2, uint4* __restrict__ p2h, int N) {
    __shared__ float sW1[64], sb1[32], sW2[HID * HID];
    int tid = threadIdx.x;
    for (int t = tid; t < HID * HID; t += 256) sW2[t] = W2[t];
    if (tid < 64) sW1[tid] = W1[tid];
    if (tid < 32) sb1[tid] = b1[tid];
    __syncthreads();
    int i = blockIdx.x * 64 + (tid >> 2);
    if (i >= N) return;
    int sub = tid & 3;

    int beg = rowptr[i], end = rowptr[i + 1];
    float ax = 0, ay = 0, bx = 0, by = 0;
    int j = beg + sub;
    for (; j + 4 < end; j += 8) {
        int c0 = col[j], c1 = col[j + 4];
        float2 v0 = p1[c0], v1 = p1[c1];
        ax += v0.x; ay += v0.y;
        bx += v1.x; by += v1.y;
    }
    if (j < end) {
        float2 v = p1[col[j]];
        ax += v.x; ay += v.y;
    }
    float sx = ax + bx, sy = ay + by;
    sx += __shfl_xor(sx, 1, 4); sy += __shfl_xor(sy, 1, 4);
    sx += __shfl_xor(sx, 2, 4); sy += __shfl_xor(sy, 2, 4);
    if (sub != 0) return;

    float2 a = p1[i];        // self term (pre-scaled)
    float di = dinv[i];
    float g0 = di * (a.x + sx);
    float g1 = di * (a.y + sy);

    // h = relu(g @ W1 + b1)
    float h[HID];
#pragma unroll
    for (int k = 0; k < HID; ++k)
        h[k] = fmaxf(g0 * sW1[k] + g1 * sW1[32 + k] + sb1[k], 0.0f);

    // o = h @ W2
    float o[HID];
#pragma unroll
    for (int f = 0; f < HID; ++f) o[f] = 0.0f;
#pragma unroll
    for (int k = 0; k < HID; ++k) {
        float hk = h[k];
#pragma unroll
        for (int f = 0; f < HID; ++f) o[f] += hk * sW2[k * HID + f];
    }

    // pack to bf16 pairs, store 4x uint4 (64B contiguous per node)
    long base16 = (long)i * 4;
#pragma unroll
    for (int q = 0; q < 4; ++q) {
        uint4 w;
        w.x = f2bf(di * o[8 * q + 0]) | (f2bf(di * o[8 * q + 1]) << 16);
        w.y = f2bf(di * o[8 * q + 2]) | (f2bf(di * o[8 * q + 3]) << 16);
        w.z = f2bf(di * o[8 * q + 4]) | (f2bf(di * o[8 * q + 5]) << 16);
        w.w = f2bf(di * o[8 * q + 6]) | (f2bf(di * o[8 * q + 7]) << 16);
        p2h[base16 + q] = w;
    }
}

// ---- layer-2 bf16 row gather: 16 lanes/node x 2 features, 4-way unrolled ----
__global__ void k_gout(const int* __restrict__ rowptr, const int* __restrict__ col,
                       const uint* __restrict__ p2h, const float* __restrict__ b2,
                       const float* __restrict__ Wp, const float* __restrict__ bp,
                       const float* __restrict__ dinv, float* __restrict__ out, int N) {
    int node = blockIdx.x * 16 + (threadIdx.x >> 4);
    if (node >= N) return;
    int hl = threadIdx.x & 15;   // owns features 2*hl, 2*hl+1
    int beg = rowptr[node], end = rowptr[node + 1];
    uint w = p2h[(long)node * 16 + hl];  // self term
    float sA0 = __uint_as_float(w << 16), sB0 = __uint_as_float(w & 0xffff0000u);
    float sA1 = 0, sB1 = 0, sA2 = 0, sB2 = 0, sA3 = 0, sB3 = 0;
    int j = beg;
    for (; j + 4 <= end; j += 4) {
        int c0 = col[j], c1 = col[j + 1], c2 = col[j + 2], c3 = col[j + 3];
        uint w0 = p2h[(long)c0 * 16 + hl];
        uint w1 = p2h[(long)c1 * 16 + hl];
        uint w2 = p2h[(long)c2 * 16 + hl];
        uint w3 = p2h[(long)c3 * 16 + hl];
        sA0 += __uint_as_float(w0 << 16); sB0 += __uint_as_float(w0 & 0xffff0000u);
        sA1 += __uint_as_float(w1 << 16); sB1 += __uint_as_float(w1 & 0xffff0000u);
        sA2 += __uint_as_float(w2 << 16); sB2 += __uint_as_float(w2 & 0xffff0000u);
        sA3 += __uint_as_float(w3 << 16); sB3 += __uint_as_float(w3 & 0xffff0000u);
    }
    for (; j < end; ++j) {
        uint wj = p2h[(long)col[j] * 16 + hl];
        sA0 += __uint_as_float(wj << 16); sB0 += __uint_as_float(wj & 0xffff0000u);
    }
    float sA = (sA0 + sA1) + (sA2 + sA3);
    float sB = (sB0 + sB1) + (sB2 + sB3);
    float di = dinv[node];
    float hvA = fmaxf(di * sA + b2[2 * hl], 0.0f);
    float hvB = fmaxf(di * sB + b2[2 * hl + 1], 0.0f);
    float v = hvA * Wp[2 * hl] + hvB * Wp[2 * hl + 1];
#pragma unroll
    for (int m = 8; m > 0; m >>= 1) v += __shfl_xor(v, m, 16);
    if (hl == 0) out[node] = 1.0f / (1.0f + expf(-(v + bp[0])));
}

extern "C" void kernel_launch(void* const* d_in, const int* in_sizes, int n_in,
                              void* d_out, int out_size, void* d_ws, size_t ws_size,
                              hipStream_t stream) {
    const float* x  = (const float*)d_in[0];
    const int*   ei = (const int*)d_in[1];
    const float* W1 = (const float*)d_in[2];
    const float* b1 = (const float*)d_in[3];
    const float* W2 = (const float*)d_in[4];
    const float* b2 = (const float*)d_in[5];
    const float* Wp = (const float*)d_in[6];
    const float* bp = (const float*)d_in[7];
    float* out = (float*)d_out;

    const int N = in_sizes[0] / 2;   // IN_DIM = 2
    const int E = in_sizes[1] / 2;   // edge_index is [2, E]
    const int* src = ei;
    const int* dst = ei + E;
    const int NB = (N + BNODES - 1) >> SH;  // 293 for N=150000 (<= NBMAX)

    // ---- workspace layout (256B aligned; bcnt+bcur adjacent for single zero pass) ----
    char* ws = (char*)d_ws;
    size_t off = 0;
    auto alloc = [&](size_t bytes) {
        void* ptr = ws + off;
        off += (bytes + 255) & ~(size_t)255;
        return ptr;
    };
    int*    bcnt   = (int*)alloc((size_t)NBMAX * 4);   // NBMAX*4 = 1280, 256-aligned
    int*    bcur   = (int*)alloc((size_t)NBMAX * 4);   // contiguous with bcnt
    int*    bbase  = (int*)alloc((size_t)(NBMAX + 1) * 4);
    int*    rowptr = (int*)alloc((size_t)(N + 1) * 4);
    float*  dinv   = (float*)alloc((size_t)N * 4);
    uint*   ebuf   = (uint*)alloc((size_t)E * 4);
    int*    col    = (int*)alloc((size_t)E * 4);
    float2* p1     = (float2*)alloc((size_t)N * 8);
    uint*   p2h    = (uint*)alloc((size_t)N * 16 * 4); // bf16 rows: 64B/node

    const int nb_t = (E + TILE - 1) / TILE;
    const int nb_g = (N + 63) / 64;      // 4 lanes/node, 64 nodes/block
    const int nb_16 = (N + 15) / 16;

    k_zero<<<(2 * NBMAX + 255) / 256, 256, 0, stream>>>(bcnt, 2 * NBMAX);
    k_bcount<<<nb_t, 512, 0, stream>>>(dst, bcnt, E, NB);
    k_scanb<<<1, 256, 0, stream>>>(bcnt, bbase, rowptr, N, NB);
    k_bucketize<<<nb_t, 512, 0, stream>>>(src, dst, bbase, bcur, ebuf, E, NB);
    k_sortb<<<NB, 512, 0, stream>>>(ebuf, bbase, x, rowptr, dinv, p1, col, N);
    k_gl12<<<nb_g, 256, 0, stream>>>(rowptr, col, p1, dinv, W1, b1, W2, (uint4*)p2h, N);
    k_gout<<<nb_16, 256, 0, stream>>>(rowptr, col, p2h, b2, Wp, bp, dinv, out, N);
}

// Round 13
// 127.574 us; speedup vs baseline: 1.2276x; 1.2276x over previous
//
#include <hip/hip_runtime.h>

#define HID 32
#define SH 9                 // bucket covers 512 nodes
#define BNODES 512
#define NBMAX 320            // >= ceil(150000/512)=293
#define TILE 8192            // edges per bucketize block

typedef unsigned int uint;

__device__ __forceinline__ uint f2bf(float v) {   // RNE f32 -> bf16 bits
    uint b = __float_as_uint(v);
    return (b + 0x7fffu + ((b >> 16) & 1u)) >> 16;
}

// ---- zero bcnt+bcur (replaces hipMemsetAsync) ----
__global__ void k_zero(int* __restrict__ p, int n) {
    int i = blockIdx.x * 256 + threadIdx.x;
    if (i < n) p[i] = 0;
}

// ---- per-tile bucket counting: LDS hist then one global atomic per bucket ----
__global__ void __launch_bounds__(512) k_bcount(const int* __restrict__ dst,
                                                int* __restrict__ bcnt, int E, int NB) {
    __shared__ int c[NBMAX];
    for (int b = threadIdx.x; b < NBMAX; b += 512) c[b] = 0;
    __syncthreads();
    int base = blockIdx.x * TILE;
    for (int k = 0; k < TILE / 512; ++k) {
        int i = base + k * 512 + threadIdx.x;
        if (i < E) atomicAdd(&c[dst[i] >> SH], 1);
    }
    __syncthreads();
    for (int b = threadIdx.x; b < NB; b += 512)
        if (c[b]) atomicAdd(&bcnt[b], c[b]);
}

// ---- exclusive scan of bucket counts; also writes rowptr[N] = E ----
__global__ void k_scanb(const int* __restrict__ bcnt, int* __restrict__ bbase,
                        int* __restrict__ rowptr, int N, int NB) {
    __shared__ int l[NBMAX + 1];
    int tid = threadIdx.x;
    if (tid < 64) {
        int lo = tid * 5;
        int s = 0;
        for (int b = lo; b < lo + 5 && b < NB; ++b) s += bcnt[b];
        int v = s;
        for (int off = 1; off < 64; off <<= 1) {
            int u = __shfl_up(v, off, 64);
            if (tid >= off) v += u;
        }
        int excl = v - s;
        for (int b = lo; b < lo + 5 && b < NB; ++b) { l[b] = excl; excl += bcnt[b]; }
        if (tid == 63) l[NB] = excl;
    }
    __syncthreads();
    for (int b = tid; b <= NB; b += blockDim.x) bbase[b] = l[b];
    if (tid == 0) rowptr[N] = l[NB];
}

// ---- bucketize: tile -> LDS counting sort by bucket -> contiguous chunk append to ebuf ----
// packed edge word: src | (dlow << 18)   (src < 2^18, dlow < 512)
__global__ void __launch_bounds__(512) k_bucketize(
        const int* __restrict__ src, const int* __restrict__ dst,
        const int* __restrict__ bbase, int* __restrict__ bcur,
        uint* __restrict__ ebuf, int E, int NB) {
    __shared__ uint  ecache[TILE];
    __shared__ unsigned short bcache[TILE];
    __shared__ int cnt[NBMAX];       // tile-local counts, then cursor
    __shared__ int loff[NBMAX + 1];  // tile-local exclusive offsets
    __shared__ int gbase[NBMAX];     // reserved global base per bucket
    int tid = threadIdx.x;
    int tbase = blockIdx.x * TILE;
    int tcount = min(E - tbase, TILE);

    for (int b = tid; b < NBMAX; b += 512) cnt[b] = 0;
    __syncthreads();
    // phase 1: count
    for (int k = 0; k < TILE / 512; ++k) {
        int i = tbase + k * 512 + tid;
        if (i < E) atomicAdd(&cnt[dst[i] >> SH], 1);
    }
    __syncthreads();
    // phase 2: scan (wave 0)
    if (tid < 64) {
        int lo = tid * 5;
        int s = 0;
        for (int b = lo; b < lo + 5 && b < NB; ++b) s += cnt[b];
        int v = s;
        for (int off = 1; off < 64; off <<= 1) {
            int u = __shfl_up(v, off, 64);
            if (tid >= off) v += u;
        }
        int excl = v - s;
        for (int b = lo; b < lo + 5 && b < NB; ++b) { loff[b] = excl; excl += cnt[b]; }
        if (tid == 63) loff[NB] = excl;
    }
    __syncthreads();
    // cursor = loff copy
    for (int b = tid; b < NB; b += 512) cnt[b] = loff[b];
    __syncthreads();
    // phase 3: place into LDS ordered by bucket
    for (int k = 0; k < TILE / 512; ++k) {
        int i = tbase + k * 512 + tid;
        if (i < E) {
            int d = dst[i];
            int b = d >> SH;
            int pos = atomicAdd(&cnt[b], 1);
            ecache[pos] = (uint)src[i] | ((uint)(d & (BNODES - 1)) << 18);
            bcache[pos] = (unsigned short)b;
        }
    }
    __syncthreads();
    // phase 4: reserve global chunks
    for (int b = tid; b < NB; b += 512) {
        int tc = loff[b + 1] - loff[b];
        if (tc > 0) gbase[b] = bbase[b] + atomicAdd(&bcur[b], tc);
    }
    __syncthreads();
    // phase 5: contiguous write-out
    for (int j = tid; j < tcount; j += 512) {
        int b = bcache[j];
        ebuf[gbase[b] + (j - loff[b])] = ecache[j];
    }
}

// ---- per-bucket counting sort by node: emits rowptr, dinv, p1 = x*dinv, dst-sorted col ----
__global__ void __launch_bounds__(512) k_sortb(
        const uint* __restrict__ ebuf, const int* __restrict__ bbase,
        const float* __restrict__ x,
        int* __restrict__ rowptr, float* __restrict__ dinv,
        float2* __restrict__ p1, int* __restrict__ col, int N) {
    __shared__ int c[BNODES];    // per-node counts
    __shared__ int off[BNODES];  // exclusive offsets within bucket
    __shared__ int cur[BNODES];  // placement cursors
    int b = blockIdx.x, tid = threadIdx.x;
    int base = bbase[b], cnt = bbase[b + 1] - base;
    for (int t = tid; t < BNODES; t += 512) c[t] = 0;
    __syncthreads();
    for (int j = tid; j < cnt; j += 512)
        atomicAdd(&c[ebuf[base + j] >> 18], 1);
    __syncthreads();
    // scan 512 counters: 64 lanes x 8 each (wave 0)
    if (tid < 64) {
        int lo = tid * 8, s = 0;
#pragma unroll
        for (int k = 0; k < 8; ++k) s += c[lo + k];
        int v = s;
        for (int o = 1; o < 64; o <<= 1) {
            int u = __shfl_up(v, o, 64);
            if (tid >= o) v += u;
        }
        int excl = v - s;
#pragma unroll
        for (int k = 0; k < 8; ++k) { off[lo + k] = excl; excl += c[lo + k]; }
    }
    __syncthreads();
    for (int t = tid; t < BNODES; t += 512) {
        cur[t] = off[t];
        int node = (b << SH) + t;
        if (node < N) {
            rowptr[node] = base + off[t];
            float di = rsqrtf((float)c[t] + 1.0f);
            dinv[node] = di;
            float2 xv = ((const float2*)x)[node];
            p1[node] = make_float2(xv.x * di, xv.y * di);
        }
    }
    __syncthreads();
    for (int j = tid; j < cnt; j += 512) {
        uint e = ebuf[base + j];
        int dl = e >> 18;
        int pos = atomicAdd(&cur[dl], 1);
        col[base + pos] = (int)(e & 0x3FFFF);
    }
}

// ---- FUSED layer-1 gather + W1/ReLU/W2/pre-scale -> packed bf16 p2 rows ----
// 8 lanes per node, LANE-DENSE throughout: lanes stride the edge list
// (coalesced col reads, 8x latency hiding); shfl-reduce the 2-wide sum;
// then EVERY lane computes a 4-feature slice of the MLP (h[4], o[4]) using
// width-8 shuffles to share the distributed h. Lane writes its uint2 slice
// (8 lanes x 8B = 64B coalesced per node). k-order ascending (numerics
// identical to the dense version).
__global__ void __launch_bounds__(256) k_gl12(
        const int* __restrict__ rowptr, const int* __restrict__ col,
        const float2* __restrict__ p1, const float* __restrict__ dinv,
        const float* __restrict__ W1, const float* __restrict__ b1,
        const float* __restrict__ W2, uint2* __restrict__ p2h, int N) {
    __shared__ float sW1[64], sb1[32], sW2[HID * HID];
    int tid = threadIdx.x;
    for (int t = tid; t < HID * HID; t += 256) sW2[t] = W2[t];
    if (tid < 64) sW1[tid] = W1[tid];
    if (tid < 32) sb1[tid] = b1[tid];
    __syncthreads();
    int i = blockIdx.x * 32 + (tid >> 3);
    if (i >= N) return;
    int sub = tid & 7;

    // --- gather: lanes stride edges, 2-way unrolled ---
    int beg = rowptr[i], end = rowptr[i + 1];
    float ax = 0, ay = 0, bx = 0, by = 0;
    int j = beg + sub;
    for (; j + 8 < end; j += 16) {
        int c0 = col[j], c1 = col[j + 8];
        float2 v0 = p1[c0], v1 = p1[c1];
        ax += v0.x; ay += v0.y;
        bx += v1.x; by += v1.y;
    }
    if (j < end) {
        float2 v = p1[col[j]];
        ax += v.x; ay += v.y;
    }
    float sx = ax + bx, sy = ay + by;
#pragma unroll
    for (int m = 1; m < 8; m <<= 1) {
        sx += __shfl_xor(sx, m, 8);
        sy += __shfl_xor(sy, m, 8);
    }

    float2 a = p1[i];        // self term (pre-scaled), broadcast load
    float di = dinv[i];
    float g0 = di * (a.x + sx);
    float g1 = di * (a.y + sy);

    // --- h slice: lane computes h[k] for k = 4*sub .. 4*sub+3 ---
    float h[4];
#pragma unroll
    for (int t = 0; t < 4; ++t) {
        int k = 4 * sub + t;
        h[t] = fmaxf(g0 * sW1[k] + g1 * sW1[32 + k] + sb1[k], 0.0f);
    }

    // --- o slice: lane computes o[f] for f = 4*sub .. 4*sub+3 ---
    // k ascending: s = source lane (k-slice owner), t = element within slice.
    float o0 = 0, o1 = 0, o2 = 0, o3 = 0;
    int fb = 4 * sub;
#pragma unroll
    for (int s = 0; s < 8; ++s) {
#pragma unroll
        for (int t = 0; t < 4; ++t) {
            float hk = __shfl(h[t], s, 8);
            int k = 4 * s + t;
            const float* wr = &sW2[k * HID + fb];
            o0 += hk * wr[0];
            o1 += hk * wr[1];
            o2 += hk * wr[2];
            o3 += hk * wr[3];
        }
    }

    // --- pack 4 features -> uint2, 8 lanes x 8B = 64B/node coalesced ---
    uint2 w;
    w.x = f2bf(di * o0) | (f2bf(di * o1) << 16);
    w.y = f2bf(di * o2) | (f2bf(di * o3) << 16);
    p2h[(long)i * 8 + sub] = w;
}

// ---- layer-2 bf16 row gather: 16 lanes/node x 2 features, 4-way unrolled ----
__global__ void k_gout(const int* __restrict__ rowptr, const int* __restrict__ col,
                       const uint* __restrict__ p2h, const float* __restrict__ b2,
                       const float* __restrict__ Wp, const float* __restrict__ bp,
                       const float* __restrict__ dinv, float* __restrict__ out, int N) {
    int node = blockIdx.x * 16 + (threadIdx.x >> 4);
    if (node >= N) return;
    int hl = threadIdx.x & 15;   // owns features 2*hl, 2*hl+1
    int beg = rowptr[node], end = rowptr[node + 1];
    uint w = p2h[(long)node * 16 + hl];  // self term
    float sA0 = __uint_as_float(w << 16), sB0 = __uint_as_float(w & 0xffff0000u);
    float sA1 = 0, sB1 = 0, sA2 = 0, sB2 = 0, sA3 = 0, sB3 = 0;
    int j = beg;
    for (; j + 4 <= end; j += 4) {
        int c0 = col[j], c1 = col[j + 1], c2 = col[j + 2], c3 = col[j + 3];
        uint w0 = p2h[(long)c0 * 16 + hl];
        uint w1 = p2h[(long)c1 * 16 + hl];
        uint w2 = p2h[(long)c2 * 16 + hl];
        uint w3 = p2h[(long)c3 * 16 + hl];
        sA0 += __uint_as_float(w0 << 16); sB0 += __uint_as_float(w0 & 0xffff0000u);
        sA1 += __uint_as_float(w1 << 16); sB1 += __uint_as_float(w1 & 0xffff0000u);
        sA2 += __uint_as_float(w2 << 16); sB2 += __uint_as_float(w2 & 0xffff0000u);
        sA3 += __uint_as_float(w3 << 16); sB3 += __uint_as_float(w3 & 0xffff0000u);
    }
    for (; j < end; ++j) {
        uint wj = p2h[(long)col[j] * 16 + hl];
        sA0 += __uint_as_float(wj << 16); sB0 += __uint_as_float(wj & 0xffff0000u);
    }
    float sA = (sA0 + sA1) + (sA2 + sA3);
    float sB = (sB0 + sB1) + (sB2 + sB3);
    float di = dinv[node];
    float hvA = fmaxf(di * sA + b2[2 * hl], 0.0f);
    float hvB = fmaxf(di * sB + b2[2 * hl + 1], 0.0f);
    float v = hvA * Wp[2 * hl] + hvB * Wp[2 * hl + 1];
#pragma unroll
    for (int m = 8; m > 0; m >>= 1) v += __shfl_xor(v, m, 16);
    if (hl == 0) out[node] = 1.0f / (1.0f + expf(-(v + bp[0])));
}

extern "C" void kernel_launch(void* const* d_in, const int* in_sizes, int n_in,
                              void* d_out, int out_size, void* d_ws, size_t ws_size,
                              hipStream_t stream) {
    const float* x  = (const float*)d_in[0];
    const int*   ei = (const int*)d_in[1];
    const float* W1 = (const float*)d_in[2];
    const float* b1 = (const float*)d_in[3];
    const float* W2 = (const float*)d_in[4];
    const float* b2 = (const float*)d_in[5];
    const float* Wp = (const float*)d_in[6];
    const float* bp = (const float*)d_in[7];
    float* out = (float*)d_out;

    const int N = in_sizes[0] / 2;   // IN_DIM = 2
    const int E = in_sizes[1] / 2;   // edge_index is [2, E]
    const int* src = ei;
    const int* dst = ei + E;
    const int NB = (N + BNODES - 1) >> SH;  // 293 for N=150000 (<= NBMAX)

    // ---- workspace layout (256B aligned; bcnt+bcur adjacent for single zero pass) ----
    char* ws = (char*)d_ws;
    size_t off = 0;
    auto alloc = [&](size_t bytes) {
        void* ptr = ws + off;
        off += (bytes + 255) & ~(size_t)255;
        return ptr;
    };
    int*    bcnt   = (int*)alloc((size_t)NBMAX * 4);   // NBMAX*4 = 1280, 256-aligned
    int*    bcur   = (int*)alloc((size_t)NBMAX * 4);   // contiguous with bcnt
    int*    bbase  = (int*)alloc((size_t)(NBMAX + 1) * 4);
    int*    rowptr = (int*)alloc((size_t)(N + 1) * 4);
    float*  dinv   = (float*)alloc((size_t)N * 4);
    uint*   ebuf   = (uint*)alloc((size_t)E * 4);
    int*    col    = (int*)alloc((size_t)E * 4);
    float2* p1     = (float2*)alloc((size_t)N * 8);
    uint*   p2h    = (uint*)alloc((size_t)N * 16 * 4); // bf16 rows: 64B/node

    const int nb_t = (E + TILE - 1) / TILE;
    const int nb_g = (N + 31) / 32;      // 8 lanes/node, 32 nodes/block
    const int nb_16 = (N + 15) / 16;

    k_zero<<<(2 * NBMAX + 255) / 256, 256, 0, stream>>>(bcnt, 2 * NBMAX);
    k_bcount<<<nb_t, 512, 0, stream>>>(dst, bcnt, E, NB);
    k_scanb<<<1, 256, 0, stream>>>(bcnt, bbase, rowptr, N, NB);
    k_bucketize<<<nb_t, 512, 0, stream>>>(src, dst, bbase, bcur, ebuf, E, NB);
    k_sortb<<<NB, 512, 0, stream>>>(ebuf, bbase, x, rowptr, dinv, p1, col, N);
    k_gl12<<<nb_g, 256, 0, stream>>>(rowptr, col, p1, dinv, W1, b1, W2, (uint2*)p2h, N);
    k_gout<<<nb_16, 256, 0, stream>>>(rowptr, col, p2h, b2, Wp, bp, dinv, out, N);
}